// Round 4
// baseline (122.349 us; speedup 1.0000x reference)
//
#include <hip/hip_runtime.h>
#include <hip/hip_fp16.h>

typedef _Float16 f16;
typedef _Float16 f16x8 __attribute__((ext_vector_type(8)));
typedef _Float16 f16x4 __attribute__((ext_vector_type(4)));
typedef float    f32x4 __attribute__((ext_vector_type(4)));

#define W1P 40                 // W1T col pitch (halves); k>=24 zero-filled
#define W2P 56                 // W2T col pitch (halves); k>=48 zero-filled
#define W1E (2*48*W1P)
#define W2E (2*96*W2P)
#define GS  152                // col-major r pitch: 304B = 19 groups, coprime w/ 8
#define HP  128                // A-frag chunk pitch: 16 rows x 8 halves = 256B

__device__ __forceinline__ float fast_tanh(float x) {
    float z = __expf(2.0f * x);
    float r = __builtin_amdgcn_rcpf(z + 1.0f);
    return __builtin_fmaf(-2.0f, r, 1.0f);
}

__global__ __launch_bounds__(256)
void setup_weights(const float* __restrict__ w01, const float* __restrict__ w11,
                   const float* __restrict__ w02, const float* __restrict__ w12,
                   f16* __restrict__ ws)
{
    const int tid0   = blockIdx.x * 256 + threadIdx.x;
    const int stride = gridDim.x * 256;
    for (int idx = tid0; idx < W1E; idx += stride) {
        const int ty  = idx / (48 * W1P);
        const int rem = idx - ty * 48 * W1P;
        const int nn  = rem / W1P, k = rem - nn * W1P;
        const float v = (k < 24) ? (ty ? w11 : w01)[k * 48 + nn] : 0.f;
        ws[idx] = (f16)v;
    }
    f16* W2T = ws + W1E;
    for (int idx = tid0; idx < W2E; idx += stride) {
        const int ty  = idx / (96 * W2P);
        const int rem = idx - ty * 96 * W2P;
        const int e   = rem / W2P, k = rem - e * W2P;
        const float v = (k < 48) ? (ty ? w12 : w02)[k * 96 + e] : 0.f;
        W2T[idx] = (f16)v;
    }
}

// rows r: 0..45 type0 (s=r), 46/47 pad; 48..139 type1 (s=r-2), 140..143 pad.
// 9 row-tiles of 16; tiles 0-2 type0, 3-8 type1. Wave w owns tiles {w, w+4, w+8}.
__global__ __launch_bounds__(256, 2)
void emb_main(const float* __restrict__ dmat,
              const float* __restrict__ w00, const float* __restrict__ b00,
              const float* __restrict__ b01, const float* __restrict__ b02,
              const float* __restrict__ w10, const float* __restrict__ b10,
              const float* __restrict__ b11, const float* __restrict__ b12,
              const f16* __restrict__ ws,
              float* __restrict__ out)
{
    __shared__ f16 H0a[9 * 3 * HP];   // tanh(L0) A-frag
    __shared__ f16 H1a[9 * 6 * HP];   // h1 (with residual) A-frag
    __shared__ f16 H1c[48 * GS];      // h1 col-major [k][r]
    __shared__ f16 T2c[96 * GS];      // tanh(L2 pre) col-major [e][r] (NO residual)
    __shared__ f16 DDT[16 * GS];      // [d(4 live)][r], pads zero
    __shared__ float Y2s[4 * 96];
    __shared__ float Y1s[4 * 48];

    const int tid  = threadIdx.x, n = blockIdx.x;
    const int wave = tid >> 6,  lane = tid & 63;
    const int l15  = lane & 15, lhi  = lane >> 4;
    const f16* __restrict__ W1T = ws;
    const f16* __restrict__ W2T = ws + W1E;

    // ---- stage 0: DDT fill (consumed only after the barrier) ----
    if (tid < GS) {
        const int r = tid;
        float4 v = make_float4(0.f, 0.f, 0.f, 0.f);
        if (r < 144) {
            const bool t0 = r < 48;
            const int  s  = t0 ? r : (r - 2);
            const bool ok = t0 ? (r < 46) : (r < 140);
            if (ok) v = *reinterpret_cast<const float4*>(dmat + (size_t)n * 552 + s * 4);
        }
        DDT[0 * GS + r] = (f16)v.x;
        DDT[1 * GS + r] = (f16)v.y;
        DDT[2 * GS + r] = (f16)v.z;
        DDT[3 * GS + r] = (f16)v.w;
#pragma unroll
        for (int d = 4; d < 16; ++d) DDT[d * GS + r] = (f16)0.f;
    }

    // ---- stages 1+2: wave-private per-tile pipeline (no barriers) ----
    for (int t = wave; t < 9; t += 4) {
        const int tyt = (t >= 3);
        const float* __restrict__ W0 = tyt ? w10 : w00;
        const float* __restrict__ B0 = tyt ? b10 : b00;
        const float* __restrict__ B1 = tyt ? b11 : b01;
        const float* __restrict__ B2 = tyt ? b12 : b02;

        // L0: lanes 0..47 (r_local = l15, k-chunk = lhi)
        if (lhi < 3) {
            const int r  = t * 16 + l15;
            const bool t0 = (t < 3);
            const int  s  = t0 ? r : (r - 2);
            const bool ok = t0 ? (r < 46) : (r < 140);
            f16x8 pk = {};
            if (ok) {
                const float x = dmat[(size_t)n * 552 + s * 4];
#pragma unroll
                for (int j = 0; j < 8; ++j)
                    pk[j] = (f16)fast_tanh(__builtin_fmaf(x, W0[lhi * 8 + j], B0[lhi * 8 + j]));
            }
            *reinterpret_cast<f16x8*>(&H0a[(t * 3 + lhi) * HP + l15 * 8]) = pk;
        }

        // L1: 3 units; h1 = tanh(acc) + h0; store A-frag + col-major
#pragma unroll
        for (int ct = 0; ct < 3; ++ct) {
            const int e1 = ct * 16 + l15;
            const float bias = B1[e1];
            f16x8 a = {};
            if (lhi < 3) a = *reinterpret_cast<const f16x8*>(&H0a[(t * 3 + lhi) * HP + l15 * 8]);
            const f16x8 b = *reinterpret_cast<const f16x8*>(&W1T[(tyt * 48 + e1) * W1P + lhi * 8]);
            f32x4 acc = {bias, bias, bias, bias};
            acc = __builtin_amdgcn_mfma_f32_16x16x32_f16(a, b, acc, 0, 0, 0);
            const int rm = (e1 < 24) ? e1 : (e1 - 24);
            const int cch = rm >> 3, cj = rm & 7;
            f16x4 hc;
#pragma unroll
            for (int rg = 0; rg < 4; ++rg) {
                const int row = lhi * 4 + rg;
                const float h0r = (float)H0a[(t * 3 + cch) * HP + row * 8 + cj];
                const float h1v = fast_tanh(acc[rg]) + h0r;
                H1a[(t * 6 + (e1 >> 3)) * HP + row * 8 + (e1 & 7)] = (f16)h1v;
                hc[rg] = (f16)h1v;
            }
            *reinterpret_cast<f16x4*>(&H1c[e1 * GS + t * 16 + lhi * 4]) = hc;
        }

        // L2: 6 units; T2 = tanh(acc) only (residual folded into stage 3)
#pragma unroll
        for (int ct = 0; ct < 6; ++ct) {
            const int e = ct * 16 + l15;
            const float bias = B2[e];
            const f16* Bp = &W2T[(tyt * 96 + e) * W2P];
            f16x8 a0 = *reinterpret_cast<const f16x8*>(&H1a[(t * 6 + lhi) * HP + l15 * 8]);
            f16x8 b0 = *reinterpret_cast<const f16x8*>(&Bp[lhi * 8]);
            f16x8 a1 = {}, b1 = {};
            if (lhi < 2) {
                a1 = *reinterpret_cast<const f16x8*>(&H1a[(t * 6 + 4 + lhi) * HP + l15 * 8]);
                b1 = *reinterpret_cast<const f16x8*>(&Bp[32 + lhi * 8]);
            }
            f32x4 acc = {bias, bias, bias, bias};
            acc = __builtin_amdgcn_mfma_f32_16x16x32_f16(a0, b0, acc, 0, 0, 0);
            acc = __builtin_amdgcn_mfma_f32_16x16x32_f16(a1, b1, acc, 0, 0, 0);
            f16x4 gp;
#pragma unroll
            for (int rg = 0; rg < 4; ++rg) gp[rg] = (f16)fast_tanh(acc[rg]);
            *reinterpret_cast<f16x4*>(&T2c[e * GS + t * 16 + lhi * 4]) = gp;
        }
    }
    __syncthreads();   // barrier #1: DDT/H1c/T2c complete

    // ---- stage 3: Y2 = DDT@T2c (u 0..5), Y1 = DDT@H1c (u 6..8); K=144 ----
    for (int u = ((wave + 1) & 3); u < 9; u += 4) {
        const f16* Bbase = (u < 6) ? &T2c[(u * 16 + l15) * GS]
                                   : &H1c[((u - 6) * 16 + l15) * GS];
        f32x4 acc = {};
#pragma unroll
        for (int st = 0; st < 4; ++st) {
            f16x8 a = *reinterpret_cast<const f16x8*>(&DDT[l15 * GS + st * 32 + lhi * 8]);
            f16x8 b = *reinterpret_cast<const f16x8*>(&Bbase[st * 32 + lhi * 8]);
            acc = __builtin_amdgcn_mfma_f32_16x16x32_f16(a, b, acc, 0, 0, 0);
        }
        {
            f16x8 a = {}, b = {};
            if (lhi < 2) {
                a = *reinterpret_cast<const f16x8*>(&DDT[l15 * GS + 128 + lhi * 8]);
                b = *reinterpret_cast<const f16x8*>(&Bbase[128 + lhi * 8]);
            }
            acc = __builtin_amdgcn_mfma_f32_16x16x32_f16(a, b, acc, 0, 0, 0);
        }
        if (lhi == 0) {
#pragma unroll
            for (int rg = 0; rg < 4; ++rg) {
                if (u < 6) Y2s[rg * 96 + u * 16 + l15] = acc[rg];
                else       Y1s[rg * 48 + (u - 6) * 16 + l15] = acc[rg];
            }
        }
    }
    __syncthreads();   // barrier #2: Y ready

    // ---- stage 4: xs = (Y2 + Y1[e mod 48])/138; res[e][k] = sum_d xs[d][e]*xs[d][k] ----
    if (tid < 96) {
        constexpr float inv = 1.0f / 138.0f;
        const int em = (tid < 48) ? tid : (tid - 48);
        const float x0 = (Y2s[      tid] + Y1s[      em]) * inv;
        const float x1 = (Y2s[ 96 + tid] + Y1s[ 48 + em]) * inv;
        const float x2 = (Y2s[192 + tid] + Y1s[ 96 + em]) * inv;
        const float x3 = (Y2s[288 + tid] + Y1s[144 + em]) * inv;
        float rv[8];
#pragma unroll
        for (int k = 0; k < 8; ++k) {
            const float k0 = (Y2s[      k] + Y1s[      k]) * inv;
            const float k1 = (Y2s[ 96 + k] + Y1s[ 48 + k]) * inv;
            const float k2 = (Y2s[192 + k] + Y1s[ 96 + k]) * inv;
            const float k3 = (Y2s[288 + k] + Y1s[144 + k]) * inv;
            float rr = x0 * k0;
            rr = __builtin_fmaf(x1, k1, rr);
            rr = __builtin_fmaf(x2, k2, rr);
            rr = __builtin_fmaf(x3, k3, rr);
            rv[k] = rr;
        }
        float* op = out + (size_t)n * 768 + tid * 8;
        *reinterpret_cast<float4*>(op)     = make_float4(rv[0], rv[1], rv[2], rv[3]);
        *reinterpret_cast<float4*>(op + 4) = make_float4(rv[4], rv[5], rv[6], rv[7]);
    }
}

extern "C" void kernel_launch(void* const* d_in, const int* in_sizes, int n_in,
                              void* d_out, int out_size, void* d_ws, size_t ws_size,
                              hipStream_t stream)
{
    const float* dmat = (const float*)d_in[0];
    const int n_atoms = in_sizes[0] / 552;   // 6144
    f16* ws = (f16*)d_ws;

    setup_weights<<<16, 256, 0, stream>>>(
        (const float*)d_in[3], (const float*)d_in[9],
        (const float*)d_in[5], (const float*)d_in[11], ws);

    emb_main<<<n_atoms, 256, 0, stream>>>(
        dmat,
        (const float*)d_in[1],  (const float*)d_in[2],   // w00, b00
        (const float*)d_in[4],  (const float*)d_in[6],   // b01, b02
        (const float*)d_in[7],  (const float*)d_in[8],   // w10, b10
        (const float*)d_in[10], (const float*)d_in[12],  // b11, b12
        ws, (float*)d_out);
}

// Round 5
// 84.624 us; speedup vs baseline: 1.4458x; 1.4458x over previous
//
#include <hip/hip_runtime.h>
#include <hip/hip_fp16.h>

typedef _Float16 f16;
typedef _Float16 f16x8 __attribute__((ext_vector_type(8)));
typedef float    f32x4 __attribute__((ext_vector_type(4)));

#define W1P 40                 // W1T col pitch (halves); k>=24 zero-filled
#define W2P 56                 // W2T col pitch (halves); k>=48 zero-filled
#define W1E (2*48*W1P)
#define W2E (2*96*W2P)
#define HP  128                // A-frag chunk pitch: 16 rows x 8 halves = 256B

__device__ __forceinline__ float fast_tanh(float x) {
    float z = __expf(2.0f * x);
    float r = __builtin_amdgcn_rcpf(z + 1.0f);
    return __builtin_fmaf(-2.0f, r, 1.0f);
}

__global__ __launch_bounds__(256)
void setup_weights(const float* __restrict__ w01, const float* __restrict__ w11,
                   const float* __restrict__ w02, const float* __restrict__ w12,
                   f16* __restrict__ ws)
{
    const int tid0   = blockIdx.x * 256 + threadIdx.x;
    const int stride = gridDim.x * 256;
    for (int idx = tid0; idx < W1E; idx += stride) {
        const int ty  = idx / (48 * W1P);
        const int rem = idx - ty * 48 * W1P;
        const int nn  = rem / W1P, k = rem - nn * W1P;
        const float v = (k < 24) ? (ty ? w11 : w01)[k * 48 + nn] : 0.f;
        ws[idx] = (f16)v;
    }
    f16* W2T = ws + W1E;
    for (int idx = tid0; idx < W2E; idx += stride) {
        const int ty  = idx / (96 * W2P);
        const int rem = idx - ty * 96 * W2P;
        const int e   = rem / W2P, k = rem - e * W2P;
        const float v = (k < 48) ? (ty ? w12 : w02)[k * 96 + e] : 0.f;
        W2T[idx] = (f16)v;
    }
}

// rows r: 0..45 type0 (s=r), 46/47 pad; 48..139 type1 (s=r-2), 140..143 pad.
// 9 row-tiles of 16; wave w (of 3) owns tiles {w, w+3, w+6} (one ty0 + two ty1 each).
__global__ __launch_bounds__(192, 4)
void emb_main(const float* __restrict__ dmat,
              const float* __restrict__ w00, const float* __restrict__ b00,
              const float* __restrict__ b01, const float* __restrict__ b02,
              const float* __restrict__ w10, const float* __restrict__ b10,
              const float* __restrict__ b11, const float* __restrict__ b12,
              const f16* __restrict__ ws,
              float* __restrict__ out)
{
    __shared__ float DD[144 * 4];      // [r][4] f32, pads zero (wave-private fill/use)
    __shared__ f16   H0a[3 * 3 * HP];  // per-wave scratch, A-frag
    __shared__ f16   H1a[3 * 6 * HP];  // per-wave scratch, A-frag
    __shared__ float Y2s[3 * 4 * 96];  // per-wave Y partials [w][d][e]

    const int tid  = threadIdx.x, n = blockIdx.x;
    const int w    = tid >> 6,  lane = tid & 63;
    const int l15  = lane & 15, lhi  = lane >> 4;
    const f16* __restrict__ W1T = ws;
    const f16* __restrict__ W2T = ws + W1E;

    // ---- DD fill: wave w fills rows of its own 3 tiles (48 rows, lanes 0..47) ----
    if (lane < 48) {
        const int t = w + 3 * (lane >> 4);
        const int r = t * 16 + (lane & 15);
        const bool t0 = (t < 3);
        const int  s  = t0 ? r : (r - 2);
        const bool ok = t0 ? (r < 46) : (r < 140);
        float4 v = make_float4(0.f, 0.f, 0.f, 0.f);
        if (ok) v = *reinterpret_cast<const float4*>(dmat + (size_t)n * 552 + s * 4);
        *reinterpret_cast<float4*>(&DD[r * 4]) = v;
    }

    float yp[24];                       // [ct][d] Y partials, f32, register-resident
#pragma unroll
    for (int i = 0; i < 24; ++i) yp[i] = 0.f;

    for (int t = w; t < 9; t += 3) {    // 3 wave-private tiles, no barriers inside
        const int tyt = (t >= 3);
        const float* __restrict__ W0 = tyt ? w10 : w00;
        const float* __restrict__ B0 = tyt ? b10 : b00;
        const float* __restrict__ B1 = tyt ? b11 : b01;
        const float* __restrict__ B2 = tyt ? b12 : b02;

        // L0: lanes lhi<3; pads get x=0 (harmless: dd=0 kills their Y contribution)
        if (lhi < 3) {
            const float x = DD[(t * 16 + l15) * 4];
            f16x8 pk;
#pragma unroll
            for (int j = 0; j < 8; ++j)
                pk[j] = (f16)fast_tanh(__builtin_fmaf(x, W0[lhi * 8 + j], B0[lhi * 8 + j]));
            *reinterpret_cast<f16x8*>(&H0a[(w * 3 + lhi) * HP + l15 * 8]) = pk;
        }

        // L1: 3 units; h1 kept in registers AND written to H1a (A-frag)
        float h1reg[12];
#pragma unroll
        for (int ct1 = 0; ct1 < 3; ++ct1) {
            const int e1 = ct1 * 16 + l15;
            const float bias = B1[e1];
            f16x8 a = {};
            if (lhi < 3) a = *reinterpret_cast<const f16x8*>(&H0a[(w * 3 + lhi) * HP + l15 * 8]);
            const f16x8 b = *reinterpret_cast<const f16x8*>(&W1T[(tyt * 48 + e1) * W1P + lhi * 8]);
            f32x4 acc = {bias, bias, bias, bias};
            acc = __builtin_amdgcn_mfma_f32_16x16x32_f16(a, b, acc, 0, 0, 0);
            const int rm = (e1 < 24) ? e1 : (e1 - 24);
            const int cch = rm >> 3, cj = rm & 7;
#pragma unroll
            for (int rg = 0; rg < 4; ++rg) {
                const int row = lhi * 4 + rg;
                const float h0r = (float)H0a[(w * 3 + cch) * HP + row * 8 + cj];
                const float h1v = fast_tanh(acc[rg]) + h0r;
                h1reg[ct1 * 4 + rg] = h1v;
                H1a[(w * 6 + (e1 >> 3)) * HP + row * 8 + (e1 & 7)] = (f16)h1v;
            }
        }

        // dd rows for this tile (broadcast within lhi group, 2-way across = free)
        float4 dd4[4];
#pragma unroll
        for (int rg = 0; rg < 4; ++rg)
            dd4[rg] = *reinterpret_cast<const float4*>(&DD[(t * 16 + lhi * 4 + rg) * 4]);

        // L2: 6 units; g = tanh(acc)+h1reg stays in f32; fused Y accumulation
#pragma unroll
        for (int ct = 0; ct < 6; ++ct) {
            const int e = ct * 16 + l15;
            const float bias = B2[e];
            const f16* Bp = &W2T[(tyt * 96 + e) * W2P];
            f16x8 a0 = *reinterpret_cast<const f16x8*>(&H1a[(w * 6 + lhi) * HP + l15 * 8]);
            f16x8 b0 = *reinterpret_cast<const f16x8*>(&Bp[lhi * 8]);
            f16x8 a1 = {}, b1 = {};
            if (lhi < 2) {
                a1 = *reinterpret_cast<const f16x8*>(&H1a[(w * 6 + 4 + lhi) * HP + l15 * 8]);
                b1 = *reinterpret_cast<const f16x8*>(&Bp[32 + lhi * 8]);
            }
            f32x4 acc = {bias, bias, bias, bias};
            acc = __builtin_amdgcn_mfma_f32_16x16x32_f16(a0, b0, acc, 0, 0, 0);
            acc = __builtin_amdgcn_mfma_f32_16x16x32_f16(a1, b1, acc, 0, 0, 0);
#pragma unroll
            for (int rg = 0; rg < 4; ++rg) {
                const float g = fast_tanh(acc[rg]) + h1reg[(ct % 3) * 4 + rg];
                yp[ct * 4 + 0] = __builtin_fmaf(dd4[rg].x, g, yp[ct * 4 + 0]);
                yp[ct * 4 + 1] = __builtin_fmaf(dd4[rg].y, g, yp[ct * 4 + 1]);
                yp[ct * 4 + 2] = __builtin_fmaf(dd4[rg].z, g, yp[ct * 4 + 2]);
                yp[ct * 4 + 3] = __builtin_fmaf(dd4[rg].w, g, yp[ct * 4 + 3]);
            }
        }
    }

    // ---- cross-lane reduce over lhi groups; lhi==0 writes per-wave partials ----
#pragma unroll
    for (int i = 0; i < 24; ++i) {
        float v = yp[i];
        v += __shfl_xor(v, 16);
        v += __shfl_xor(v, 32);
        yp[i] = v;
    }
    if (lhi == 0) {
#pragma unroll
        for (int ct = 0; ct < 6; ++ct)
#pragma unroll
            for (int d = 0; d < 4; ++d)
                Y2s[w * 384 + d * 96 + ct * 16 + l15] = yp[ct * 4 + d];
    }
    __syncthreads();   // the only block-wide barrier

    // ---- stage 4: xs = (sum_w Y)/138; res[e][k] = sum_d xs[d][e]*xs[d][k] ----
    if (tid < 96) {
        constexpr float inv = 1.0f / 138.0f;
        float x0 = (Y2s[tid]        + Y2s[384 + tid]        + Y2s[768 + tid])        * inv;
        float x1 = (Y2s[96 + tid]   + Y2s[384 + 96 + tid]   + Y2s[768 + 96 + tid])   * inv;
        float x2 = (Y2s[192 + tid]  + Y2s[384 + 192 + tid]  + Y2s[768 + 192 + tid])  * inv;
        float x3 = (Y2s[288 + tid]  + Y2s[384 + 288 + tid]  + Y2s[768 + 288 + tid])  * inv;
        float rv[8];
#pragma unroll
        for (int k = 0; k < 8; ++k) {   // same-address reads -> LDS broadcast
            const float k0 = (Y2s[k]       + Y2s[384 + k]       + Y2s[768 + k])       * inv;
            const float k1 = (Y2s[96 + k]  + Y2s[384 + 96 + k]  + Y2s[768 + 96 + k])  * inv;
            const float k2 = (Y2s[192 + k] + Y2s[384 + 192 + k] + Y2s[768 + 192 + k]) * inv;
            const float k3 = (Y2s[288 + k] + Y2s[384 + 288 + k] + Y2s[768 + 288 + k]) * inv;
            float rr = x0 * k0;
            rr = __builtin_fmaf(x1, k1, rr);
            rr = __builtin_fmaf(x2, k2, rr);
            rr = __builtin_fmaf(x3, k3, rr);
            rv[k] = rr;
        }
        float* op = out + (size_t)n * 768 + tid * 8;
        *reinterpret_cast<float4*>(op)     = make_float4(rv[0], rv[1], rv[2], rv[3]);
        *reinterpret_cast<float4*>(op + 4) = make_float4(rv[4], rv[5], rv[6], rv[7]);
    }
}

extern "C" void kernel_launch(void* const* d_in, const int* in_sizes, int n_in,
                              void* d_out, int out_size, void* d_ws, size_t ws_size,
                              hipStream_t stream)
{
    const float* dmat = (const float*)d_in[0];
    const int n_atoms = in_sizes[0] / 552;   // 6144
    f16* ws = (f16*)d_ws;

    setup_weights<<<16, 256, 0, stream>>>(
        (const float*)d_in[3], (const float*)d_in[9],
        (const float*)d_in[5], (const float*)d_in[11], ws);

    emb_main<<<n_atoms, 192, 0, stream>>>(
        dmat,
        (const float*)d_in[1],  (const float*)d_in[2],   // w00, b00
        (const float*)d_in[4],  (const float*)d_in[6],   // b01, b02
        (const float*)d_in[7],  (const float*)d_in[8],   // w10, b10
        (const float*)d_in[10], (const float*)d_in[12],  // b11, b12
        ws, (float*)d_out);
}